// Round 15
// baseline (608.061 us; speedup 1.0000x reference)
//
#include <hip/hip_runtime.h>

typedef unsigned short ushortT;
typedef _Float16 halfT;
typedef _Float16 f16x8 __attribute__((ext_vector_type(8)));
typedef float f32x4 __attribute__((ext_vector_type(4)));
typedef float f32x16 __attribute__((ext_vector_type(16)));
typedef unsigned int u32x4 __attribute__((ext_vector_type(4)));

// EqProp free phase, B=4096, layers [10,512,512 | x=784 clamped], T=30, DT=0.5.
// States stay in [0,1] => rho(s)=s, rhop(s)=1. FP16 states+weights (R14 proven,
// absmax 0.0039), fp32 c2. This round: 32x32x16 MFMAs in the step kernel —
// 2x FLOP/instr and 2x FLOP per LDS byte vs 16x16x32; per-iter wave cost drops
// 10 ds_read+8 MFMA -> 8 ds_read+4 MFMA. Structure otherwise identical to R14.
// State: fp16 plane, row stride 1056: [0,10)=s0, [32,544)=s1, [544,1056)=s2.
#define HSTR 1056
#define OFF1B 32
#define OFF2B 544
#define CSTR 1034

__device__ __forceinline__ void split2h(float f, halfT& h, halfT& l) {
    h = (halfT)f;
    l = (halfT)(f - (float)h);
}

#define MFMA16(a, b, c) __builtin_amdgcn_mfma_f32_16x16x32_f16(a, b, c, 0, 0, 0)
#define MFMA32(a, b, c) __builtin_amdgcn_mfma_f32_32x32x16_f16(a, b, c, 0, 0, 0)
#define BCAST(x) __builtin_bit_cast(f16x8, x)

// ---------------- zero state buffer A ----------------
__global__ void k_zero(u32x4* __restrict__ p, int n) {
    u32x4 z = {0u, 0u, 0u, 0u};
    for (int i = blockIdx.x * blockDim.x + threadIdx.x; i < n; i += gridDim.x * blockDim.x)
        p[i] = z;
}

// ---------------- W1 -> fp16 row-major + fp16 transpose ----------------
__global__ __launch_bounds__(256) void k_prep(const float* __restrict__ W1,
                                              halfT* __restrict__ W1h,
                                              halfT* __restrict__ W1T) {
    __shared__ float tile[64][65];
    const int ti = blockIdx.x >> 3, tj = blockIdx.x & 7;
    const int t = threadIdx.x;
#pragma unroll
    for (int q = 0; q < 16; ++q) {
        int rr = q * 4 + (t >> 6), cc = t & 63;
        float v = W1[(size_t)(ti * 64 + rr) * 512 + tj * 64 + cc];
        tile[rr][cc] = v;
        W1h[(size_t)(ti * 64 + rr) * 512 + tj * 64 + cc] = (halfT)v;
    }
    __syncthreads();
#pragma unroll
    for (int q = 0; q < 16; ++q) {
        int rr = q * 4 + (t >> 6), cc = t & 63;
        W1T[(size_t)(tj * 64 + rr) * 512 + ti * 64 + cc] = (halfT)tile[cc][rr];
    }
}

// ---------------- c2 = rho(x) @ W2^T + b2 via split-fp16 MFMA (3-pass) ----------------
__global__ __launch_bounds__(256) void k_c2(const float* __restrict__ x,
                                            const float* __restrict__ W2,
                                            const float* __restrict__ b2,
                                            float* __restrict__ c2) {
    __shared__ u32x4 cs[2048];
    u32x4* xHi = cs;
    u32x4* xLo = cs + 512;
    u32x4* wHi = cs + 1024;
    u32x4* wLo = cs + 1536;
    const int bid = blockIdx.x, t = threadIdx.x;
    const int lane = t & 63, w = t >> 6, l15 = lane & 15, l4 = lane >> 4;
    const int bm2 = (bid >> 3) * 64, bn2 = (bid & 7) * 64;
    const int mB2 = (w >> 1) * 32, nB2 = (w & 1) * 32;
    const int sr2 = t >> 2, ub = (t & 3) * 2;
    f32x4 accC[2][2];
#pragma unroll
    for (int i = 0; i < 2; ++i)
#pragma unroll
        for (int j = 0; j < 2; ++j) { f32x4 z = {0.f, 0.f, 0.f, 0.f}; accC[i][j] = z; }
    for (int k0 = 0; k0 < 784; k0 += 64) {
#pragma unroll
        for (int j = 0; j < 2; ++j) {
            int u = ub + j;
            bool valid = (k0 + u * 8 + 8 <= 784);
            union { halfT hs[8]; u32x4 v; } ph, pl, qh, ql;
            if (valid) {
                const float* srcx = x  + (size_t)(bm2 + sr2) * 784 + k0 + u * 8;
                const float* srcw = W2 + (size_t)(bn2 + sr2) * 784 + k0 + u * 8;
#pragma unroll
                for (int e = 0; e < 8; ++e) {
                    float cx = fminf(fmaxf(srcx[e], 0.f), 1.f);
                    split2h(cx, ph.hs[e], pl.hs[e]);
                    split2h(srcw[e], qh.hs[e], ql.hs[e]);
                }
            } else {
#pragma unroll
                for (int e = 0; e < 8; ++e) {
                    ph.hs[e] = (halfT)0.f; pl.hs[e] = (halfT)0.f;
                    qh.hs[e] = (halfT)0.f; ql.hs[e] = (halfT)0.f;
                }
            }
            int sw = u ^ (sr2 & 7);
            xHi[sr2 * 8 + sw] = ph.v;  xLo[sr2 * 8 + sw] = pl.v;
            wHi[sr2 * 8 + sw] = qh.v;  wLo[sr2 * 8 + sw] = ql.v;
        }
        __syncthreads();
        int kwMax = (k0 == 768) ? 1 : 2;
        for (int kw = 0; kw < kwMax; ++kw) {
            f16x8 ah[2], al[2], bh[2], bl[2];
#pragma unroll
            for (int i = 0; i < 2; ++i) {
                int m = mB2 + i * 16 + l15;
                int uu = (kw * 4 + l4) ^ (m & 7);
                ah[i] = BCAST(xHi[m * 8 + uu]);
                al[i] = BCAST(xLo[m * 8 + uu]);
                int n = nB2 + i * 16 + l15;
                int uv = (kw * 4 + l4) ^ (n & 7);
                bh[i] = BCAST(wHi[n * 8 + uv]);
                bl[i] = BCAST(wLo[n * 8 + uv]);
            }
#pragma unroll
            for (int i = 0; i < 2; ++i)
#pragma unroll
                for (int jj = 0; jj < 2; ++jj) {
                    accC[i][jj] = MFMA16(ah[i], bh[jj], accC[i][jj]);
                    accC[i][jj] = MFMA16(al[i], bh[jj], accC[i][jj]);
                    accC[i][jj] = MFMA16(ah[i], bl[jj], accC[i][jj]);
                }
        }
        __syncthreads();
    }
#pragma unroll
    for (int mi = 0; mi < 2; ++mi)
#pragma unroll
        for (int ni = 0; ni < 2; ++ni)
#pragma unroll
            for (int q = 0; q < 4; ++q) {
                int row = bm2 + mB2 + mi * 16 + l4 * 4 + q;
                int col = bn2 + nB2 + ni * 16 + l15;
                c2[(size_t)row * 512 + col] = accC[mi][ni][q] + b2[col];
            }
}

// ---------------- per-step fused kernel: fp16, 32x32x16 MFMAs ----------------
// 512 blocks x 512 thr (8 waves; wave = 32 rows x 32 cols of the 128x64 tile).
// z1 (256 blocks): new s1; z2 (256): new s2; z2&bn0 also z0 (16x16 path).
// XCD affinity via xcd = bid&7.
__global__ __launch_bounds__(512, 4) void k_step7(const halfT* __restrict__ sH,
                                                  halfT* __restrict__ dH,
                                                  const halfT* __restrict__ W1h,
                                                  const halfT* __restrict__ W1T,
                                                  const float* __restrict__ W0,
                                                  const float* __restrict__ b0,
                                                  const float* __restrict__ b1,
                                                  const float* __restrict__ c2,
                                                  float* __restrict__ outF) {
    __shared__ u32x4 smem[2560];     // 40 KiB
    u32x4* AsR = smem;               // 1024: A tile [128 rows][8 units], swizzled
    u32x4* BhS = smem + 1024;        //  512: W tile [64][8]
    u32x4* aux = smem + 1536;        // 1024: doZ0 -> Bz0[16][64]; z1 -> Bs2[0..255]+As2[256..767]

    const int bid = blockIdx.x, t = threadIdx.x;
    const int lane = t & 63, w = t >> 6;
    const int l15 = lane & 15, l4 = lane >> 4;
    const int l31 = lane & 31, lh = lane >> 5;
    const int mB = (w >> 1) * 32;    // wave rows [mB, mB+32)
    const int nB = (w & 1) * 32;     // wave cols [nB, nB+32)
    const bool cg0 = (w & 1) == 0;

    const int xcd = bid & 7, rblk = bid >> 3, bn_i = rblk & 7, grp = rblk >> 3;
    const int pidx = grp * 8 + xcd;
    const bool isZ1 = pidx < 32;
    const int bm = (pidx & 31) * 128, bn = bn_i * 64;
    const bool doZ0 = (!isZ1) && (bn_i == 0);

    // ---- aux LDS staging (published by the K-loop's first barrier) ----
    if (isZ1) {
        if (t < 256) {   // Bs2[n][u]: B[n][k] = W0[k][bn+n], K=32 window (10 real)
            int n = t >> 2, u = t & 3;
            union { halfT hs[8]; u32x4 v; } pk;
#pragma unroll
            for (int e = 0; e < 8; ++e) {
                int k = u * 8 + e;
                pk.hs[e] = (k < 10) ? (halfT)W0[(size_t)k * 512 + bn + n] : (halfT)0.f;
            }
            aux[n * 4 + u] = pk.v;
        }
        if (t < 128) {   // As2[row][u]: s0 window, zero-padded to K=32
            union { halfT hs[16]; u32x4 v2[2]; } pk;
#pragma unroll
            for (int e = 0; e < 16; ++e) pk.hs[e] = (halfT)0.f;
            const halfT* sp = sH + (size_t)(bm + t) * HSTR;
#pragma unroll
            for (int e = 0; e < 10; ++e) pk.hs[e] = sp[e];
            u32x4 z = {0u, 0u, 0u, 0u};
            aux[256 + t * 4 + 0] = pk.v2[0];
            aux[256 + t * 4 + 1] = pk.v2[1];
            aux[256 + t * 4 + 2] = z;
            aux[256 + t * 4 + 3] = z;
        }
    } else if (doZ0) {   // Bz0[c][64 units]: W0^T, 16 cols x K=512, swizzled
        int c = t >> 5, u0 = (t & 31) * 2;
#pragma unroll
        for (int j = 0; j < 2; ++j) {
            int U = u0 + j;
            union { halfT hs[8]; u32x4 v; } pk;
#pragma unroll
            for (int e = 0; e < 8; ++e)
                pk.hs[e] = (c < 10) ? (halfT)W0[(size_t)c * 512 + U * 8 + e] : (halfT)0.f;
            aux[c * 64 + ((U & ~7) | ((U & 7) ^ (c & 7)))] = pk.v;
        }
    }

    const int aOff = isZ1 ? OFF2B : OFF1B;   // z1 reads s2, z2 reads s1
    const int dOff = isZ1 ? OFF1B : OFF2B;   // dest layer
    const int oOff = isZ1 ? 10 : 522;
    const halfT* __restrict__ Wb = isZ1 ? W1h : W1T;
    const int sr = t >> 2, su = (t & 3) * 2;     // A staging: 4 thr/row, 2 units each
    const int bnr = t >> 3, bju = t & 7;         // B staging: 8 thr/row, 1 unit each
    const bool fin = (outF != nullptr);

    f32x16 acc;
#pragma unroll
    for (int i = 0; i < 16; ++i) acc[i] = 0.f;
    f32x4 accZ[2];
#pragma unroll
    for (int h = 0; h < 2; ++h) { f32x4 z = {0.f,0.f,0.f,0.f}; accZ[h] = z; }

    // ---- software-pipelined K loop: 8 iters of BK=64, reg-staged double buffer ----
    u32x4 rA[2][2], rB[2];
    {
        const u32x4* gA = (const u32x4*)(sH + (size_t)(bm + sr) * HSTR + aOff);
        rA[0][0] = gA[su];  rA[0][1] = gA[su + 1];
        rB[0] = ((const u32x4*)(Wb + (size_t)(bn + bnr) * 512))[bju];
    }
#pragma unroll
    for (int it = 0; it < 8; ++it) {
        const int k0 = it * 64;
        const int cur = it & 1, nxt = cur ^ 1;
        __syncthreads();                      // prev compute done; LDS reusable
        AsR[sr * 8 + ( su      ^ (sr & 7))] = rA[cur][0];
        AsR[sr * 8 + ((su + 1) ^ (sr & 7))] = rA[cur][1];
        BhS[bnr * 8 + (bju ^ (bnr & 7))] = rB[cur];
        if (it < 7) {                         // prefetch next K tile into regs
            const int k1 = k0 + 64;
            const u32x4* gA = (const u32x4*)(sH + (size_t)(bm + sr) * HSTR + aOff + k1);
            rA[nxt][0] = gA[su];  rA[nxt][1] = gA[su + 1];
            rB[nxt] = ((const u32x4*)(Wb + (size_t)(bn + bnr) * 512 + k1))[bju];
        }
        __syncthreads();                      // publish LDS
        // main: 4 x (K=16) 32x32 MFMAs
#pragma unroll
        for (int j = 0; j < 4; ++j) {
            int m = mB + l31;
            int n = nB + l31;
            int u = j * 2 + lh;
            f16x8 a = BCAST(AsR[m * 8 + (u ^ (m & 7))]);
            f16x8 b = BCAST(BhS[n * 8 + (u ^ (n & 7))]);
            acc = MFMA32(a, b, acc);
        }
        if (doZ0 && cg0) {   // z0: 16x16 path, rows mB..mB+31 in two halves
#pragma unroll
            for (int kw = 0; kw < 2; ++kw) {
                int U = it * 8 + kw * 4 + l4;
                f16x8 bz = BCAST(aux[l15 * 64 + ((U & ~7) | ((U & 7) ^ (l15 & 7)))]);
#pragma unroll
                for (int h = 0; h < 2; ++h) {
                    int m = mB + h * 16 + l15;
                    f16x8 a16 = BCAST(AsR[m * 8 + ((kw * 4 + l4) ^ (m & 7))]);
                    accZ[h] = MFMA16(a16, bz, accZ[h]);
                }
            }
        }
    }
    if (isZ1) {   // s0 @ W0 extra window: ONE 32x32x16 MFMA (k 0..15, 10 real)
        f16x8 a0 = BCAST(aux[256 + (size_t)(mB + l31) * 4 + lh]);
        f16x8 bb = BCAST(aux[(size_t)(nB + l31) * 4 + lh]);
        acc = MFMA32(a0, bb, acc);
    }

    // ---- epilogue: v = clip(0.5*old + 0.5*(acc + bias)) ----
    // 32x32 C layout: col = nB + (lane&31), row = mB + (i&3) + 8*(i>>2) + 4*lh
    __syncthreads();   // all LDS reads done; AsR reusable as output staging
    const int gc = bn + nB + l31;
    const float biasN = isZ1 ? b1[gc] : 0.f;
    if (fin) {
#pragma unroll
        for (int i = 0; i < 16; ++i) {
            int rloc = mB + (i & 3) + 8 * (i >> 2) + 4 * lh;
            size_t row = (size_t)bm + rloc;
            float bias = isZ1 ? biasN : c2[row * 512 + gc];
            float old = (float)sH[row * HSTR + dOff + gc];
            float v = 0.5f * old + 0.5f * (acc[i] + bias);
            v = fminf(fmaxf(v, 0.f), 1.f);
            outF[row * CSTR + oOff + gc] = v;
        }
        if (doZ0 && cg0 && l15 < 10) {
            float b0v = b0[l15];
#pragma unroll
            for (int h = 0; h < 2; ++h)
#pragma unroll
                for (int q = 0; q < 4; ++q) {
                    size_t row = (size_t)bm + mB + h * 16 + l4 * 4 + q;
                    float old = (float)sH[row * HSTR + l15];
                    float v = 0.5f * old + 0.5f * (accZ[h][q] + b0v);
                    v = fminf(fmaxf(v, 0.f), 1.f);
                    outF[row * CSTR + l15] = v;
                }
        }
    } else {
        halfT* dlds = (halfT*)AsR;   // 128x64 fp16 output tile
#pragma unroll
        for (int i = 0; i < 16; ++i) {
            int rloc = mB + (i & 3) + 8 * (i >> 2) + 4 * lh;
            size_t row = (size_t)bm + rloc;
            float bias = isZ1 ? biasN : c2[row * 512 + gc];
            float old = (float)sH[row * HSTR + dOff + gc];
            float v = 0.5f * old + 0.5f * (acc[i] + bias);
            v = fminf(fmaxf(v, 0.f), 1.f);
            dlds[rloc * 64 + nB + l31] = (halfT)v;
        }
        if (doZ0 && cg0 && l15 < 10) {
            float b0v = b0[l15];
#pragma unroll
            for (int h = 0; h < 2; ++h)
#pragma unroll
                for (int q = 0; q < 4; ++q) {
                    size_t row = (size_t)bm + mB + h * 16 + l4 * 4 + q;
                    float old = (float)sH[row * HSTR + l15];
                    float v = 0.5f * old + 0.5f * (accZ[h][q] + b0v);
                    v = fminf(fmaxf(v, 0.f), 1.f);
                    dH[row * HSTR + l15] = (halfT)v;
                }
        }
        __syncthreads();
        // coalesced 16B-per-lane tile store into this block's column slice
#pragma unroll
        for (int j = 0; j < 2; ++j) {
            int i = j * 512 + t;
            int row = i >> 3, u = i & 7;
            ((u32x4*)(dH + (size_t)(bm + row) * HSTR + dOff + bn))[u] = AsR[i];
        }
    }
}

extern "C" void kernel_launch(void* const* d_in, const int* in_sizes, int n_in,
                              void* d_out, int out_size, void* d_ws, size_t ws_size,
                              hipStream_t stream) {
    const float* x  = (const float*)d_in[3];
    const float* W0 = (const float*)d_in[4];
    const float* b0 = (const float*)d_in[5];
    const float* W1 = (const float*)d_in[6];
    const float* b1 = (const float*)d_in[7];
    const float* W2 = (const float*)d_in[8];
    const float* b2 = (const float*)d_in[9];

    // buffer A in d_out: 4096*1056*2 = 8,650,752 B <= 16,943,104 B
    halfT* hiA = (halfT*)d_out;
    // ws: hiB | c2 f32 | W1h fp16 | W1T fp16  (~17.7 MB)
    halfT* hiB = (halfT*)d_ws;
    float* c2  = (float*)(hiB + (size_t)4096 * HSTR);
    halfT* W1h = (halfT*)(c2 + (size_t)4096 * 512);
    halfT* W1T = W1h + 512 * 512;

    const int zeroN = (int)((size_t)4096 * HSTR * sizeof(halfT) / sizeof(u32x4));
    k_zero<<<1024, 256, 0, stream>>>((u32x4*)hiA, zeroN);
    k_prep<<<64, 256, 0, stream>>>(W1, W1h, W1T);
    k_c2<<<512, 256, 0, stream>>>(x, W2, b2, c2);

    for (int ts = 0; ts < 30; ++ts) {
        const halfT* sH = (ts & 1) ? hiB : hiA;
        halfT* dH       = (ts & 1) ? hiA : hiB;
        float* outF = (ts == 29) ? (float*)d_out : nullptr;
        k_step7<<<512, 512, 0, stream>>>(sH, dH, W1h, W1T, W0, b0, b1, c2, outF);
    }
}

// Round 16
// 598.313 us; speedup vs baseline: 1.0163x; 1.0163x over previous
//
#include <hip/hip_runtime.h>

typedef unsigned short ushortT;
typedef _Float16 halfT;
typedef _Float16 f16x8 __attribute__((ext_vector_type(8)));
typedef float f32x4 __attribute__((ext_vector_type(4)));
typedef unsigned int u32x4 __attribute__((ext_vector_type(4)));

// EqProp free phase, B=4096, layers [10,512,512 | x=784 clamped], T=30, DT=0.5.
// States stay in [0,1] => rho(s)=s, rhop(s)=1. FP16 states+weights (R14 proven,
// absmax 0.0039, 548us), fp32 c2. This round: (a) BK=128 in the step kernel —
// halves barriers/staging rounds; grid already caps residency at 2 blocks/CU so
// the 64KB LDS costs nothing; (b) single-pass fp16 c2 (error ~1e-4, 3x fewer
// MFMAs in prologue). 16x16x32 MFMAs, structure otherwise identical to R14.
// State: fp16 plane, row stride 1056: [0,10)=s0, [32,544)=s1, [544,1056)=s2.
#define HSTR 1056
#define OFF1B 32
#define OFF2B 544
#define CSTR 1034

#define MFMA16(a, b, c) __builtin_amdgcn_mfma_f32_16x16x32_f16(a, b, c, 0, 0, 0)
#define BCAST(x) __builtin_bit_cast(f16x8, x)
// swizzle for 16-unit rows: XOR row bits into low-3 unit bits
#define SWZ(u, r) (((u) & 8) | (((u) & 7) ^ ((r) & 7)))

// ---------------- zero state buffer A ----------------
__global__ void k_zero(u32x4* __restrict__ p, int n) {
    u32x4 z = {0u, 0u, 0u, 0u};
    for (int i = blockIdx.x * blockDim.x + threadIdx.x; i < n; i += gridDim.x * blockDim.x)
        p[i] = z;
}

// ---------------- W1 -> fp16 row-major + fp16 transpose ----------------
__global__ __launch_bounds__(256) void k_prep(const float* __restrict__ W1,
                                              halfT* __restrict__ W1h,
                                              halfT* __restrict__ W1T) {
    __shared__ float tile[64][65];
    const int ti = blockIdx.x >> 3, tj = blockIdx.x & 7;
    const int t = threadIdx.x;
#pragma unroll
    for (int q = 0; q < 16; ++q) {
        int rr = q * 4 + (t >> 6), cc = t & 63;
        float v = W1[(size_t)(ti * 64 + rr) * 512 + tj * 64 + cc];
        tile[rr][cc] = v;
        W1h[(size_t)(ti * 64 + rr) * 512 + tj * 64 + cc] = (halfT)v;
    }
    __syncthreads();
#pragma unroll
    for (int q = 0; q < 16; ++q) {
        int rr = q * 4 + (t >> 6), cc = t & 63;
        W1T[(size_t)(tj * 64 + rr) * 512 + ti * 64 + cc] = (halfT)tile[cc][rr];
    }
}

// ---------------- c2 = rho(x) @ W2^T + b2, single-pass fp16 MFMA ----------------
__global__ __launch_bounds__(256) void k_c2(const float* __restrict__ x,
                                            const float* __restrict__ W2,
                                            const float* __restrict__ b2,
                                            float* __restrict__ c2) {
    __shared__ u32x4 cs[1024];
    u32x4* xS = cs;            // [64][8]
    u32x4* wS = cs + 512;      // [64][8]
    const int bid = blockIdx.x, t = threadIdx.x;
    const int lane = t & 63, w = t >> 6, l15 = lane & 15, l4 = lane >> 4;
    const int bm2 = (bid >> 3) * 64, bn2 = (bid & 7) * 64;
    const int mB2 = (w >> 1) * 32, nB2 = (w & 1) * 32;
    const int sr2 = t >> 2, ub = (t & 3) * 2;
    f32x4 accC[2][2];
#pragma unroll
    for (int i = 0; i < 2; ++i)
#pragma unroll
        for (int j = 0; j < 2; ++j) { f32x4 z = {0.f, 0.f, 0.f, 0.f}; accC[i][j] = z; }
    for (int k0 = 0; k0 < 784; k0 += 64) {
#pragma unroll
        for (int j = 0; j < 2; ++j) {
            int u = ub + j;
            bool valid = (k0 + u * 8 + 8 <= 784);
            union { halfT hs[8]; u32x4 v; } px, pw;
            if (valid) {
                const float* srcx = x  + (size_t)(bm2 + sr2) * 784 + k0 + u * 8;
                const float* srcw = W2 + (size_t)(bn2 + sr2) * 784 + k0 + u * 8;
#pragma unroll
                for (int e = 0; e < 8; ++e) {
                    px.hs[e] = (halfT)fminf(fmaxf(srcx[e], 0.f), 1.f);
                    pw.hs[e] = (halfT)srcw[e];
                }
            } else {
#pragma unroll
                for (int e = 0; e < 8; ++e) { px.hs[e] = (halfT)0.f; pw.hs[e] = (halfT)0.f; }
            }
            int sw = u ^ (sr2 & 7);
            xS[sr2 * 8 + sw] = px.v;
            wS[sr2 * 8 + sw] = pw.v;
        }
        __syncthreads();
        int kwMax = (k0 == 768) ? 1 : 2;
        for (int kw = 0; kw < kwMax; ++kw) {
            f16x8 a[2], b[2];
#pragma unroll
            for (int i = 0; i < 2; ++i) {
                int m = mB2 + i * 16 + l15;
                a[i] = BCAST(xS[m * 8 + ((kw * 4 + l4) ^ (m & 7))]);
                int n = nB2 + i * 16 + l15;
                b[i] = BCAST(wS[n * 8 + ((kw * 4 + l4) ^ (n & 7))]);
            }
#pragma unroll
            for (int i = 0; i < 2; ++i)
#pragma unroll
                for (int jj = 0; jj < 2; ++jj)
                    accC[i][jj] = MFMA16(a[i], b[jj], accC[i][jj]);
        }
        __syncthreads();
    }
#pragma unroll
    for (int mi = 0; mi < 2; ++mi)
#pragma unroll
        for (int ni = 0; ni < 2; ++ni)
#pragma unroll
            for (int q = 0; q < 4; ++q) {
                int row = bm2 + mB2 + mi * 16 + l4 * 4 + q;
                int col = bn2 + nB2 + ni * 16 + l15;
                c2[(size_t)row * 512 + col] = accC[mi][ni][q] + b2[col];
            }
}

// ---------------- per-step fused kernel: fp16, BK=128 ----------------
// 512 blocks x 512 thr (8 waves; wave = 16 rows x 64 cols of the 128x64 tile).
// z1 (256 blocks): new s1; z2 (256): new s2; z2&bn0 also z0.
// XCD affinity via xcd = bid&7. K loop: 4 iters of BK=128, 2 barriers each.
__global__ __launch_bounds__(512, 4) void k_step8(const halfT* __restrict__ sH,
                                                  halfT* __restrict__ dH,
                                                  const halfT* __restrict__ W1h,
                                                  const halfT* __restrict__ W1T,
                                                  const float* __restrict__ W0,
                                                  const float* __restrict__ b0,
                                                  const float* __restrict__ b1,
                                                  const float* __restrict__ c2,
                                                  float* __restrict__ outF) {
    __shared__ u32x4 smem[4096];     // 64 KiB (static >64KB-class OK per R6/R11)
    u32x4* AsR = smem;               // 2048: A tile [128 rows][16 units], swizzled
    u32x4* BhS = smem + 2048;        // 1024: W tile [64][16]
    u32x4* aux = smem + 3072;        // 1024: doZ0 -> Bz0[16][64]; z1 -> Bs2[0..255]+As2[256..767]

    const int bid = blockIdx.x, t = threadIdx.x;
    const int lane = t & 63, w = t >> 6, l15 = lane & 15, l4 = lane >> 4;
    const int mB = w * 16;           // wave rows [mB, mB+16)

    const int xcd = bid & 7, rblk = bid >> 3, bn_i = rblk & 7, grp = rblk >> 3;
    const int pidx = grp * 8 + xcd;
    const bool isZ1 = pidx < 32;
    const int bm = (pidx & 31) * 128, bn = bn_i * 64;
    const bool doZ0 = (!isZ1) && (bn_i == 0);

    // ---- aux LDS staging (published by the K-loop's first barrier) ----
    if (isZ1) {
        if (t < 256) {   // Bs2[n][u]: B[n][k] = W0[k][bn+n], K=32 window (10 real)
            int n = t >> 2, u = t & 3;
            union { halfT hs[8]; u32x4 v; } pk;
#pragma unroll
            for (int e = 0; e < 8; ++e) {
                int k = u * 8 + e;
                pk.hs[e] = (k < 10) ? (halfT)W0[(size_t)k * 512 + bn + n] : (halfT)0.f;
            }
            aux[n * 4 + u] = pk.v;
        }
        if (t < 128) {   // As2[row][u]: s0 window, zero-padded to K=32
            union { halfT hs[16]; u32x4 v2[2]; } pk;
#pragma unroll
            for (int e = 0; e < 16; ++e) pk.hs[e] = (halfT)0.f;
            const halfT* sp = sH + (size_t)(bm + t) * HSTR;
#pragma unroll
            for (int e = 0; e < 10; ++e) pk.hs[e] = sp[e];
            u32x4 z = {0u, 0u, 0u, 0u};
            aux[256 + t * 4 + 0] = pk.v2[0];
            aux[256 + t * 4 + 1] = pk.v2[1];
            aux[256 + t * 4 + 2] = z;
            aux[256 + t * 4 + 3] = z;
        }
    } else if (doZ0) {   // Bz0[c][64 units]: W0^T, 16 cols x K=512, swizzled
        int c = t >> 5, u0 = (t & 31) * 2;
#pragma unroll
        for (int j = 0; j < 2; ++j) {
            int U = u0 + j;
            union { halfT hs[8]; u32x4 v; } pk;
#pragma unroll
            for (int e = 0; e < 8; ++e)
                pk.hs[e] = (c < 10) ? (halfT)W0[(size_t)c * 512 + U * 8 + e] : (halfT)0.f;
            aux[c * 64 + ((U & ~7) | ((U & 7) ^ (c & 7)))] = pk.v;
        }
    }

    const int aOff = isZ1 ? OFF2B : OFF1B;   // z1 reads s2, z2 reads s1
    const int dOff = isZ1 ? OFF1B : OFF2B;   // dest layer
    const int oOff = isZ1 ? 10 : 522;
    const halfT* __restrict__ Wb = isZ1 ? W1h : W1T;
    const int sr = t >> 2, su = (t & 3) * 4;     // A staging: 4 thr/row, 4 units each
    const int bnr = t >> 3, bju = (t & 7) * 2;   // B staging: 8 thr/row, 2 units each
    const bool fin = (outF != nullptr);

    f32x4 acc[4], accZ;
#pragma unroll
    for (int ni = 0; ni < 4; ++ni) { f32x4 z = {0.f,0.f,0.f,0.f}; acc[ni] = z; }
    { f32x4 z = {0.f,0.f,0.f,0.f}; accZ = z; }

    // ---- software-pipelined K loop: 4 iters of BK=128, reg-staged double buffer ----
    u32x4 rA[2][4], rB[2][2];
    {
        const u32x4* gA = (const u32x4*)(sH + (size_t)(bm + sr) * HSTR + aOff);
        const u32x4* gB = (const u32x4*)(Wb + (size_t)(bn + bnr) * 512);
#pragma unroll
        for (int j = 0; j < 4; ++j) rA[0][j] = gA[su + j];
#pragma unroll
        for (int j = 0; j < 2; ++j) rB[0][j] = gB[bju + j];
    }
#pragma unroll
    for (int it = 0; it < 4; ++it) {
        const int k0 = it * 128;
        const int cur = it & 1, nxt = cur ^ 1;
        __syncthreads();                      // prev compute done; LDS reusable
#pragma unroll
        for (int j = 0; j < 4; ++j)
            AsR[sr * 16 + SWZ(su + j, sr)] = rA[cur][j];
#pragma unroll
        for (int j = 0; j < 2; ++j)
            BhS[bnr * 16 + SWZ(bju + j, bnr)] = rB[cur][j];
        if (it < 3) {                         // prefetch next K tile into regs
            const int k1 = k0 + 128;
            const u32x4* gA = (const u32x4*)(sH + (size_t)(bm + sr) * HSTR + aOff + k1);
            const u32x4* gB = (const u32x4*)(Wb + (size_t)(bn + bnr) * 512 + k1);
#pragma unroll
            for (int j = 0; j < 4; ++j) rA[nxt][j] = gA[su + j];
#pragma unroll
            for (int j = 0; j < 2; ++j) rB[nxt][j] = gB[bju + j];
        }
        __syncthreads();                      // publish LDS
#pragma unroll
        for (int kw = 0; kw < 4; ++kw) {
            f16x8 a, b[4];
            {
                int m = mB + l15;
                a = BCAST(AsR[m * 16 + SWZ(kw * 4 + l4, m)]);
            }
#pragma unroll
            for (int ni = 0; ni < 4; ++ni) {
                int n = ni * 16 + l15;
                b[ni] = BCAST(BhS[n * 16 + SWZ(kw * 4 + l4, n)]);
            }
#pragma unroll
            for (int ni = 0; ni < 4; ++ni)
                acc[ni] = MFMA16(a, b[ni], acc[ni]);
            if (doZ0) {
                int U = it * 16 + kw * 4 + l4;
                f16x8 bz = BCAST(aux[l15 * 64 + ((U & ~7) | ((U & 7) ^ (l15 & 7)))]);
                accZ = MFMA16(a, bz, accZ);
            }
        }
    }
    if (isZ1) {   // s0 @ W0 extra K=32 window
        f16x8 a2 = BCAST(aux[256 + (size_t)(mB + l15) * 4 + l4]);
#pragma unroll
        for (int ni = 0; ni < 4; ++ni) {
            f16x8 bb = BCAST(aux[(size_t)(ni * 16 + l15) * 4 + l4]);
            acc[ni] = MFMA16(a2, bb, acc[ni]);
        }
    }

    // ---- epilogue: v = clip(0.5*old + 0.5*(acc + bias)) ----
    __syncthreads();   // all LDS reads done; AsR reusable as output staging
    if (fin) {
#pragma unroll
        for (int ni = 0; ni < 4; ++ni) {
            int gc = bn + ni * 16 + l15;
            float biasN = isZ1 ? b1[gc] : 0.f;
#pragma unroll
            for (int q = 0; q < 4; ++q) {
                size_t row = (size_t)bm + mB + l4 * 4 + q;
                float bias = isZ1 ? biasN : c2[row * 512 + gc];
                float old = (float)sH[row * HSTR + dOff + gc];
                float v = 0.5f * old + 0.5f * (acc[ni][q] + bias);
                v = fminf(fmaxf(v, 0.f), 1.f);
                outF[row * CSTR + oOff + gc] = v;
            }
        }
        if (doZ0 && l15 < 10) {
            float b0v = b0[l15];
#pragma unroll
            for (int q = 0; q < 4; ++q) {
                size_t row = (size_t)bm + mB + l4 * 4 + q;
                float old = (float)sH[row * HSTR + l15];
                float v = 0.5f * old + 0.5f * (accZ[q] + b0v);
                v = fminf(fmaxf(v, 0.f), 1.f);
                outF[row * CSTR + l15] = v;
            }
        }
    } else {
        halfT* dlds = (halfT*)AsR;   // 128x64 fp16 output tile
#pragma unroll
        for (int ni = 0; ni < 4; ++ni) {
            int gc = bn + ni * 16 + l15;
            float biasN = isZ1 ? b1[gc] : 0.f;
#pragma unroll
            for (int q = 0; q < 4; ++q) {
                size_t row = (size_t)bm + mB + l4 * 4 + q;
                float bias = isZ1 ? biasN : c2[row * 512 + gc];
                float old = (float)sH[row * HSTR + dOff + gc];
                float v = 0.5f * old + 0.5f * (acc[ni][q] + bias);
                v = fminf(fmaxf(v, 0.f), 1.f);
                dlds[(mB + l4 * 4 + q) * 64 + ni * 16 + l15] = (halfT)v;
            }
        }
        if (doZ0 && l15 < 10) {
            float b0v = b0[l15];
#pragma unroll
            for (int q = 0; q < 4; ++q) {
                size_t row = (size_t)bm + mB + l4 * 4 + q;
                float old = (float)sH[row * HSTR + l15];
                float v = 0.5f * old + 0.5f * (accZ[q] + b0v);
                v = fminf(fmaxf(v, 0.f), 1.f);
                dH[row * HSTR + l15] = (halfT)v;
            }
        }
        __syncthreads();
        // coalesced 16B-per-lane tile store into this block's column slice
#pragma unroll
        for (int j = 0; j < 2; ++j) {
            int i = j * 512 + t;
            int row = i >> 3, u = i & 7;
            ((u32x4*)(dH + (size_t)(bm + row) * HSTR + dOff + bn))[u] = AsR[i];
        }
    }
}

extern "C" void kernel_launch(void* const* d_in, const int* in_sizes, int n_in,
                              void* d_out, int out_size, void* d_ws, size_t ws_size,
                              hipStream_t stream) {
    const float* x  = (const float*)d_in[3];
    const float* W0 = (const float*)d_in[4];
    const float* b0 = (const float*)d_in[5];
    const float* W1 = (const float*)d_in[6];
    const float* b1 = (const float*)d_in[7];
    const float* W2 = (const float*)d_in[8];
    const float* b2 = (const float*)d_in[9];

    // buffer A in d_out: 4096*1056*2 = 8,650,752 B <= 16,943,104 B
    halfT* hiA = (halfT*)d_out;
    // ws: hiB | c2 f32 | W1h fp16 | W1T fp16  (~17.7 MB)
    halfT* hiB = (halfT*)d_ws;
    float* c2  = (float*)(hiB + (size_t)4096 * HSTR);
    halfT* W1h = (halfT*)(c2 + (size_t)4096 * 512);
    halfT* W1T = W1h + 512 * 512;

    const int zeroN = (int)((size_t)4096 * HSTR * sizeof(halfT) / sizeof(u32x4));
    k_zero<<<1024, 256, 0, stream>>>((u32x4*)hiA, zeroN);
    k_prep<<<64, 256, 0, stream>>>(W1, W1h, W1T);
    k_c2<<<512, 256, 0, stream>>>(x, W2, b2, c2);

    for (int ts = 0; ts < 30; ++ts) {
        const halfT* sH = (ts & 1) ? hiB : hiA;
        halfT* dH       = (ts & 1) ? hiA : hiB;
        float* outF = (ts == 29) ? (float*)d_out : nullptr;
        k_step8<<<512, 512, 0, stream>>>(sH, dH, W1h, W1T, W0, b0, b1, c2, outF);
    }
}

// Round 17
// 541.280 us; speedup vs baseline: 1.1234x; 1.1054x over previous
//
#include <hip/hip_runtime.h>

typedef unsigned short ushortT;
typedef _Float16 halfT;
typedef _Float16 f16x8 __attribute__((ext_vector_type(8)));
typedef float f32x4 __attribute__((ext_vector_type(4)));
typedef unsigned int u32x4 __attribute__((ext_vector_type(4)));

// EqProp free phase, B=4096, layers [10,512,512 | x=784 clamped], T=30, DT=0.5.
// States stay in [0,1] => rho(s)=s, rhop(s)=1.
// FINAL CONSOLIDATION: R14's proven k_step6 (fp16 states+weights, BK=64,
// 16x16x32 MFMA, 8 waves x 16x64 sub-tiles, reg-staged dbuf, 548us) +
// R16's proven single-pass fp16 c2 (same absmax 0.0039, ~20us cheaper).
// State: fp16 plane, row stride 1056: [0,10)=s0, [32,544)=s1, [544,1056)=s2.
#define HSTR 1056
#define OFF1B 32
#define OFF2B 544
#define CSTR 1034

#define MFMA16(a, b, c) __builtin_amdgcn_mfma_f32_16x16x32_f16(a, b, c, 0, 0, 0)
#define BCAST(x) __builtin_bit_cast(f16x8, x)

// ---------------- zero state buffer A ----------------
__global__ void k_zero(u32x4* __restrict__ p, int n) {
    u32x4 z = {0u, 0u, 0u, 0u};
    for (int i = blockIdx.x * blockDim.x + threadIdx.x; i < n; i += gridDim.x * blockDim.x)
        p[i] = z;
}

// ---------------- W1 -> fp16 row-major + fp16 transpose ----------------
__global__ __launch_bounds__(256) void k_prep(const float* __restrict__ W1,
                                              halfT* __restrict__ W1h,
                                              halfT* __restrict__ W1T) {
    __shared__ float tile[64][65];
    const int ti = blockIdx.x >> 3, tj = blockIdx.x & 7;
    const int t = threadIdx.x;
#pragma unroll
    for (int q = 0; q < 16; ++q) {
        int rr = q * 4 + (t >> 6), cc = t & 63;
        float v = W1[(size_t)(ti * 64 + rr) * 512 + tj * 64 + cc];
        tile[rr][cc] = v;
        W1h[(size_t)(ti * 64 + rr) * 512 + tj * 64 + cc] = (halfT)v;
    }
    __syncthreads();
#pragma unroll
    for (int q = 0; q < 16; ++q) {
        int rr = q * 4 + (t >> 6), cc = t & 63;
        W1T[(size_t)(tj * 64 + rr) * 512 + ti * 64 + cc] = (halfT)tile[cc][rr];
    }
}

// ---------------- c2 = rho(x) @ W2^T + b2, single-pass fp16 MFMA (R16 proven) --------
__global__ __launch_bounds__(256) void k_c2(const float* __restrict__ x,
                                            const float* __restrict__ W2,
                                            const float* __restrict__ b2,
                                            float* __restrict__ c2) {
    __shared__ u32x4 cs[1024];
    u32x4* xS = cs;            // [64][8]
    u32x4* wS = cs + 512;      // [64][8]
    const int bid = blockIdx.x, t = threadIdx.x;
    const int lane = t & 63, w = t >> 6, l15 = lane & 15, l4 = lane >> 4;
    const int bm2 = (bid >> 3) * 64, bn2 = (bid & 7) * 64;
    const int mB2 = (w >> 1) * 32, nB2 = (w & 1) * 32;
    const int sr2 = t >> 2, ub = (t & 3) * 2;
    f32x4 accC[2][2];
#pragma unroll
    for (int i = 0; i < 2; ++i)
#pragma unroll
        for (int j = 0; j < 2; ++j) { f32x4 z = {0.f, 0.f, 0.f, 0.f}; accC[i][j] = z; }
    for (int k0 = 0; k0 < 784; k0 += 64) {
#pragma unroll
        for (int j = 0; j < 2; ++j) {
            int u = ub + j;
            bool valid = (k0 + u * 8 + 8 <= 784);
            union { halfT hs[8]; u32x4 v; } px, pw;
            if (valid) {
                const float* srcx = x  + (size_t)(bm2 + sr2) * 784 + k0 + u * 8;
                const float* srcw = W2 + (size_t)(bn2 + sr2) * 784 + k0 + u * 8;
#pragma unroll
                for (int e = 0; e < 8; ++e) {
                    px.hs[e] = (halfT)fminf(fmaxf(srcx[e], 0.f), 1.f);
                    pw.hs[e] = (halfT)srcw[e];
                }
            } else {
#pragma unroll
                for (int e = 0; e < 8; ++e) { px.hs[e] = (halfT)0.f; pw.hs[e] = (halfT)0.f; }
            }
            int sw = u ^ (sr2 & 7);
            xS[sr2 * 8 + sw] = px.v;
            wS[sr2 * 8 + sw] = pw.v;
        }
        __syncthreads();
        int kwMax = (k0 == 768) ? 1 : 2;
        for (int kw = 0; kw < kwMax; ++kw) {
            f16x8 a[2], b[2];
#pragma unroll
            for (int i = 0; i < 2; ++i) {
                int m = mB2 + i * 16 + l15;
                a[i] = BCAST(xS[m * 8 + ((kw * 4 + l4) ^ (m & 7))]);
                int n = nB2 + i * 16 + l15;
                b[i] = BCAST(wS[n * 8 + ((kw * 4 + l4) ^ (n & 7))]);
            }
#pragma unroll
            for (int i = 0; i < 2; ++i)
#pragma unroll
                for (int jj = 0; jj < 2; ++jj)
                    accC[i][jj] = MFMA16(a[i], b[jj], accC[i][jj]);
        }
        __syncthreads();
    }
#pragma unroll
    for (int mi = 0; mi < 2; ++mi)
#pragma unroll
        for (int ni = 0; ni < 2; ++ni)
#pragma unroll
            for (int q = 0; q < 4; ++q) {
                int row = bm2 + mB2 + mi * 16 + l4 * 4 + q;
                int col = bn2 + nB2 + ni * 16 + l15;
                c2[(size_t)row * 512 + col] = accC[mi][ni][q] + b2[col];
            }
}

// ---------------- per-step fused kernel: fp16, R14 structure (proven 548us) ----------
// 512 blocks x 512 thr (8 waves; wave = 16 rows x 64 cols). z1 (256 blocks):
// new s1 tile; z2 (256): new s2; z2&bn0 also z0. XCD affinity via xcd = bid&7.
__global__ __launch_bounds__(512, 4) void k_step6(const halfT* __restrict__ sH,
                                                  halfT* __restrict__ dH,
                                                  const halfT* __restrict__ W1h,
                                                  const halfT* __restrict__ W1T,
                                                  const float* __restrict__ W0,
                                                  const float* __restrict__ b0,
                                                  const float* __restrict__ b1,
                                                  const float* __restrict__ c2,
                                                  float* __restrict__ outF) {
    __shared__ u32x4 smem[2560];     // 40 KiB
    u32x4* AsR = smem;               // 1024: A tile [128 rows][8 units], swizzled
    u32x4* BhS = smem + 1024;        //  512: W tile [64][8]
    u32x4* aux = smem + 1536;        // 1024: doZ0 -> Bz0[16][64]; z1 -> Bs2[0..255]+As2[256..767]

    const int bid = blockIdx.x, t = threadIdx.x;
    const int lane = t & 63, w = t >> 6, l15 = lane & 15, l4 = lane >> 4;
    const int mB = w * 16;           // wave rows [mB, mB+16)

    const int xcd = bid & 7, rblk = bid >> 3, bn_i = rblk & 7, grp = rblk >> 3;
    const int pidx = grp * 8 + xcd;
    const bool isZ1 = pidx < 32;
    const int bm = (pidx & 31) * 128, bn = bn_i * 64;
    const bool doZ0 = (!isZ1) && (bn_i == 0);

    // ---- aux LDS staging (published by the K-loop's first barrier) ----
    if (isZ1) {
        if (t < 256) {   // Bs2[n][u]: B[n][k] = W0[k][bn+n], K=32 window (10 real)
            int n = t >> 2, u = t & 3;
            union { halfT hs[8]; u32x4 v; } pk;
#pragma unroll
            for (int e = 0; e < 8; ++e) {
                int k = u * 8 + e;
                pk.hs[e] = (k < 10) ? (halfT)W0[(size_t)k * 512 + bn + n] : (halfT)0.f;
            }
            aux[n * 4 + u] = pk.v;
        }
        if (t < 128) {   // As2[row][u]: s0 window, zero-padded to K=32
            union { halfT hs[16]; u32x4 v2[2]; } pk;
#pragma unroll
            for (int e = 0; e < 16; ++e) pk.hs[e] = (halfT)0.f;
            const halfT* sp = sH + (size_t)(bm + t) * HSTR;
#pragma unroll
            for (int e = 0; e < 10; ++e) pk.hs[e] = sp[e];
            u32x4 z = {0u, 0u, 0u, 0u};
            aux[256 + t * 4 + 0] = pk.v2[0];
            aux[256 + t * 4 + 1] = pk.v2[1];
            aux[256 + t * 4 + 2] = z;
            aux[256 + t * 4 + 3] = z;
        }
    } else if (doZ0) {   // Bz0[c][64 units]: W0^T, 16 cols x K=512, swizzled
        int c = t >> 5, u0 = (t & 31) * 2;
#pragma unroll
        for (int j = 0; j < 2; ++j) {
            int U = u0 + j;
            union { halfT hs[8]; u32x4 v; } pk;
#pragma unroll
            for (int e = 0; e < 8; ++e)
                pk.hs[e] = (c < 10) ? (halfT)W0[(size_t)c * 512 + U * 8 + e] : (halfT)0.f;
            aux[c * 64 + ((U & ~7) | ((U & 7) ^ (c & 7)))] = pk.v;
        }
    }

    const int aOff = isZ1 ? OFF2B : OFF1B;   // z1 reads s2, z2 reads s1
    const int dOff = isZ1 ? OFF1B : OFF2B;   // dest layer
    const int oOff = isZ1 ? 10 : 522;
    const halfT* __restrict__ Wb = isZ1 ? W1h : W1T;
    const int sr = t >> 2, su = (t & 3) * 2;     // A staging: 4 thr/row, 2 units each
    const int bnr = t >> 3, bju = t & 7;         // B staging: 8 thr/row, 1 unit each
    const bool fin = (outF != nullptr);

    f32x4 acc[4], accZ;
#pragma unroll
    for (int ni = 0; ni < 4; ++ni) { f32x4 z = {0.f,0.f,0.f,0.f}; acc[ni] = z; }
    { f32x4 z = {0.f,0.f,0.f,0.f}; accZ = z; }

    // ---- software-pipelined K loop: 8 iters of BK=64, reg-staged double buffer ----
    u32x4 rA[2][2], rB[2];
    {
        const u32x4* gA = (const u32x4*)(sH + (size_t)(bm + sr) * HSTR + aOff);
        rA[0][0] = gA[su];  rA[0][1] = gA[su + 1];
        rB[0] = ((const u32x4*)(Wb + (size_t)(bn + bnr) * 512))[bju];
    }
#pragma unroll
    for (int it = 0; it < 8; ++it) {
        const int k0 = it * 64;
        const int cur = it & 1, nxt = cur ^ 1;
        __syncthreads();                      // prev compute done; LDS reusable
        AsR[sr * 8 + ( su      ^ (sr & 7))] = rA[cur][0];
        AsR[sr * 8 + ((su + 1) ^ (sr & 7))] = rA[cur][1];
        BhS[bnr * 8 + (bju ^ (bnr & 7))] = rB[cur];
        if (it < 7) {                         // prefetch next K tile into regs
            const int k1 = k0 + 64;
            const u32x4* gA = (const u32x4*)(sH + (size_t)(bm + sr) * HSTR + aOff + k1);
            rA[nxt][0] = gA[su];  rA[nxt][1] = gA[su + 1];
            rB[nxt] = ((const u32x4*)(Wb + (size_t)(bn + bnr) * 512 + k1))[bju];
        }
        __syncthreads();                      // publish LDS
#pragma unroll
        for (int kw = 0; kw < 2; ++kw) {
            f16x8 a, b[4];
            {
                int m = mB + l15;
                a = BCAST(AsR[m * 8 + ((kw * 4 + l4) ^ (m & 7))]);
            }
#pragma unroll
            for (int ni = 0; ni < 4; ++ni) {
                int n = ni * 16 + l15;
                b[ni] = BCAST(BhS[n * 8 + ((kw * 4 + l4) ^ (n & 7))]);
            }
#pragma unroll
            for (int ni = 0; ni < 4; ++ni)
                acc[ni] = MFMA16(a, b[ni], acc[ni]);
            if (doZ0) {
                int U = it * 8 + kw * 4 + l4;
                f16x8 bz = BCAST(aux[l15 * 64 + ((U & ~7) | ((U & 7) ^ (l15 & 7)))]);
                accZ = MFMA16(a, bz, accZ);
            }
        }
    }
    if (isZ1) {   // s0 @ W0 extra K=32 window
        f16x8 a2 = BCAST(aux[256 + (size_t)(mB + l15) * 4 + l4]);
#pragma unroll
        for (int ni = 0; ni < 4; ++ni) {
            f16x8 bb = BCAST(aux[(size_t)(ni * 16 + l15) * 4 + l4]);
            acc[ni] = MFMA16(a2, bb, acc[ni]);
        }
    }

    // ---- epilogue: v = clip(0.5*old + 0.5*(acc + bias)) ----
    __syncthreads();   // all LDS reads done; AsR reusable as output staging
    if (fin) {
#pragma unroll
        for (int ni = 0; ni < 4; ++ni) {
            int gc = bn + ni * 16 + l15;
            float biasN = isZ1 ? b1[gc] : 0.f;
#pragma unroll
            for (int q = 0; q < 4; ++q) {
                size_t row = (size_t)bm + mB + l4 * 4 + q;
                float bias = isZ1 ? biasN : c2[row * 512 + gc];
                float old = (float)sH[row * HSTR + dOff + gc];
                float v = 0.5f * old + 0.5f * (acc[ni][q] + bias);
                v = fminf(fmaxf(v, 0.f), 1.f);
                outF[row * CSTR + oOff + gc] = v;
            }
        }
        if (doZ0 && l15 < 10) {
            float b0v = b0[l15];
#pragma unroll
            for (int q = 0; q < 4; ++q) {
                size_t row = (size_t)bm + mB + l4 * 4 + q;
                float old = (float)sH[row * HSTR + l15];
                float v = 0.5f * old + 0.5f * (accZ[q] + b0v);
                v = fminf(fmaxf(v, 0.f), 1.f);
                outF[row * CSTR + l15] = v;
            }
        }
    } else {
        halfT* dlds = (halfT*)AsR;   // 128x64 fp16 output tile
#pragma unroll
        for (int ni = 0; ni < 4; ++ni) {
            int gc = bn + ni * 16 + l15;
            float biasN = isZ1 ? b1[gc] : 0.f;
#pragma unroll
            for (int q = 0; q < 4; ++q) {
                size_t row = (size_t)bm + mB + l4 * 4 + q;
                float bias = isZ1 ? biasN : c2[row * 512 + gc];
                float old = (float)sH[row * HSTR + dOff + gc];
                float v = 0.5f * old + 0.5f * (acc[ni][q] + bias);
                v = fminf(fmaxf(v, 0.f), 1.f);
                dlds[(mB + l4 * 4 + q) * 64 + ni * 16 + l15] = (halfT)v;
            }
        }
        if (doZ0 && l15 < 10) {
            float b0v = b0[l15];
#pragma unroll
            for (int q = 0; q < 4; ++q) {
                size_t row = (size_t)bm + mB + l4 * 4 + q;
                float old = (float)sH[row * HSTR + l15];
                float v = 0.5f * old + 0.5f * (accZ[q] + b0v);
                v = fminf(fmaxf(v, 0.f), 1.f);
                dH[row * HSTR + l15] = (halfT)v;
            }
        }
        __syncthreads();
        // coalesced 16B-per-lane tile store into this block's column slice
#pragma unroll
        for (int j = 0; j < 2; ++j) {
            int i = j * 512 + t;
            int row = i >> 3, u = i & 7;
            ((u32x4*)(dH + (size_t)(bm + row) * HSTR + dOff + bn))[u] = AsR[i];
        }
    }
}

extern "C" void kernel_launch(void* const* d_in, const int* in_sizes, int n_in,
                              void* d_out, int out_size, void* d_ws, size_t ws_size,
                              hipStream_t stream) {
    const float* x  = (const float*)d_in[3];
    const float* W0 = (const float*)d_in[4];
    const float* b0 = (const float*)d_in[5];
    const float* W1 = (const float*)d_in[6];
    const float* b1 = (const float*)d_in[7];
    const float* W2 = (const float*)d_in[8];
    const float* b2 = (const float*)d_in[9];

    // buffer A in d_out: 4096*1056*2 = 8,650,752 B <= 16,943,104 B
    halfT* hiA = (halfT*)d_out;
    // ws: hiB | c2 f32 | W1h fp16 | W1T fp16  (~17.7 MB)
    halfT* hiB = (halfT*)d_ws;
    float* c2  = (float*)(hiB + (size_t)4096 * HSTR);
    halfT* W1h = (halfT*)(c2 + (size_t)4096 * 512);
    halfT* W1T = W1h + 512 * 512;

    const int zeroN = (int)((size_t)4096 * HSTR * sizeof(halfT) / sizeof(u32x4));
    k_zero<<<1024, 256, 0, stream>>>((u32x4*)hiA, zeroN);
    k_prep<<<64, 256, 0, stream>>>(W1, W1h, W1T);
    k_c2<<<512, 256, 0, stream>>>(x, W2, b2, c2);

    for (int ts = 0; ts < 30; ++ts) {
        const halfT* sH = (ts & 1) ? hiB : hiA;
        halfT* dH       = (ts & 1) ? hiA : hiB;
        float* outF = (ts == 29) ? (float*)d_out : nullptr;
        k_step6<<<512, 512, 0, stream>>>(sH, dH, W1h, W1T, W0, b0, b1, c2, outF);
    }
}